// Round 13
// baseline (4223.376 us; speedup 1.0000x reference)
//
#include <hip/hip_runtime.h>

#define BB 512
#define TT 2048
#define DD 8
#define HH 64
#define NB 16               // batch columns per tile
#define NTILE (BB / NB)     // 32 tiles -> 64 blocks (producer+consumer pairs)
#define PIPE 4              // ring slots per tile (power of 2)
#define SLOT_B 2048         // bytes per slot: 16 rows x 128 B (fp16 h0, frag layout)
#define RING_OFF 4096       // ring starts after the flag page in d_ws
#define SPIN_MAX (1 << 16)  // bounded spin: broken handshake => fast wrong answer, never a hang

typedef _Float16 f16x8 __attribute__((ext_vector_type(8)));
typedef __fp16   fp16x2 __attribute__((ext_vector_type(2)));
typedef float    f32x4 __attribute__((ext_vector_type(4)));

__device__ __forceinline__ float rcpf(float x) { return __builtin_amdgcn_rcpf(x); }
__device__ __forceinline__ float sigm(float x) { return rcpf(1.0f + __expf(-x)); }
__device__ __forceinline__ float tanh_fast(float x) {
  return 1.0f - 2.0f * rcpf(__expf(2.0f * x) + 1.0f);
}
__device__ __forceinline__ f16x8 cvt8(const float* __restrict__ p) {
  f16x8 r;
#pragma unroll
  for (int e = 0; e < 8; ++e) r[e] = (_Float16)p[e];
  return r;
}
__device__ __forceinline__ uint2 pk4(float a, float b, float c, float d) {
  union { fp16x2 h2[2]; uint2 u; } P;
  P.h2[0] = __builtin_amdgcn_cvt_pkrtz(a, b);
  P.h2[1] = __builtin_amdgcn_cvt_pkrtz(c, d);
  return P.u;
}

// device-scope (AGENT) ring accesses: bypass per-XCD L2 so the consumer
// reads L3-fresh data; release/acquire on the flags provide ordering.
__device__ __forceinline__ void st64(void* p, unsigned long long v) {
  __hip_atomic_store((unsigned long long*)p, v, __ATOMIC_RELAXED, __HIP_MEMORY_SCOPE_AGENT);
}
__device__ __forceinline__ unsigned long long ld64(const void* p) {
  return __hip_atomic_load((unsigned long long*)p, __ATOMIC_RELAXED, __HIP_MEMORY_SCOPE_AGENT);
}

// R13 = hardened R12 resubmit (R12 hit the ambiguous "container failed"
// signature also seen in R2/R10; R10's identical-content resubmit ran fine).
// Hardening: spin bound 2^20 -> 2^16 (total worst-case spin <5s, fast-wrong
// instead of timeout-kill if the handshake were broken).
//
// Design: PRODUCER/CONSUMER SPLIT ACROSS CUs. R11's counters show active-CU
// VALUBusy ~70% (8.8 x 256/32): issue-bound on 32 CUs, 224 idle. Within-CU
// reshuffles conserve per-SIMD issue (R11: -7%). 64 blocks (even = L0
// producer, odd = L1 consumer, same batch tile) halve per-CU issue work.
// h0[t] flows through a 4-slot AGENT-scope ring in d_ws (L3-resident);
// consumer prefetches h0[s+1] a full body (~1000 cyc) before use.
// Handshake (monotone, deadlock-free): producer@t waits cf>=t-3; consumer
// sets cf=s+2 after loading step s+1; consumer waits pf>=s+2; producer sets
// pf=t+1 after its stores drain at __syncthreads.
__global__ void __launch_bounds__(256, 1)
lstm2_pc(const float* __restrict__ x,
         const float* __restrict__ w_ih0, const float* __restrict__ w_hh0,
         const float* __restrict__ b_ih0, const float* __restrict__ b_hh0,
         const float* __restrict__ w_ih1, const float* __restrict__ w_hh1,
         const float* __restrict__ b_ih1, const float* __restrict__ b_hh1,
         const float* __restrict__ w_out, const float* __restrict__ b_out,
         float* __restrict__ out,
         int* __restrict__ flags, unsigned char* __restrict__ ring)
{
  const int tid  = threadIdx.x;
  const int lane = tid & 63;
  const int q    = tid >> 6;    // wave 0..3
  const int lg   = lane >> 4;   // k-group 0..3
  const int ar   = lane & 15;   // A-row / B-col / batch n
  const int tile = blockIdx.x >> 1;
  const int role = blockIdx.x & 1;   // 0 = L0 producer, 1 = L1 consumer

  __shared__ __align__(16) unsigned char hbuf[2][NB][128];  // own-layer parity dbuf
  __shared__ float hout[HH][NB];

  {  // zero parity buffers (h[-1] reads as 0)
    float* z = (float*)hbuf;
    for (int i = tid; i < (int)(sizeof(hbuf) / 4); i += 256) z[i] = 0.f;
  }

  const int k0  = 16 * q + 4 * lg;
  const int pub = 16 * ((k0 >> 3) ^ (ar & 7)) + 2 * (k0 & 7);   // 8B aligned
  const int rd0 = 16 * ((0 + lg) ^ (ar & 7));
  const int rd1 = 16 * ((4 + lg) ^ (ar & 7));

  unsigned char* myring = ring + (size_t)tile * (PIPE * SLOT_B);
  int* pf = flags + tile;           // producer progress: steps < pf published
  int* cf = flags + NTILE + tile;   // consumer progress: loaded through (cf-1)

  if (role == 0) {
    // ================= producer: layer 0 =================
    f16x8 a_x[4], aU[4][2];
    f32x4 bC[4];
#pragma unroll
    for (int ti = 0; ti < 4; ++ti) {
      const int tile_m = q + 4 * ti;
      const int ga = 16 * tile_m + ar;
      f16x8 zf = {};
      a_x[ti] = zf;
      if (lg == 0) a_x[ti] = cvt8(w_ih0 + ga * DD);
#pragma unroll
      for (int kf = 0; kf < 2; ++kf)
        aU[ti][kf] = cvt8(w_hh0 + ga * HH + kf * 32 + lg * 8);
#pragma unroll
      for (int r = 0; r < 4; ++r) {
        const int gc = 16 * tile_m + 4 * lg + r;
        bC[ti][r] = b_ih0[gc] + b_hh0[gc];
      }
    }
    const float4* xrow =
        (const float4*)(x + (size_t)(tile * NB + ar) * TT * DD);
    float4 xA = xrow[0], xB = xrow[1];
    float cv[4] = {0.f, 0.f, 0.f, 0.f};
    int cached_cons = 0;
    __syncthreads();

    for (int t = 0; t < TT; ++t) {
      const int p = t & 1, rp = p ^ 1;
      const f16x8 hf0_0 = *(const f16x8*)&hbuf[rp][ar][rd0];
      const f16x8 hf0_1 = *(const f16x8*)&hbuf[rp][ar][rd1];

      f16x8 xf = {};
      if (lg == 0) {
        union { fp16x2 h2[4]; f16x8 v; } X;
        X.h2[0] = __builtin_amdgcn_cvt_pkrtz(xA.x, xA.y);
        X.h2[1] = __builtin_amdgcn_cvt_pkrtz(xA.z, xA.w);
        X.h2[2] = __builtin_amdgcn_cvt_pkrtz(xB.x, xB.y);
        X.h2[3] = __builtin_amdgcn_cvt_pkrtz(xB.z, xB.w);
        xf = X.v;
      }
      {
        const int tn = (t + 1 < TT) ? (t + 1) : (TT - 1);
        xA = xrow[2 * tn];
        xB = xrow[2 * tn + 1];
      }

      f32x4 acc[4];
#pragma unroll
      for (int ti = 0; ti < 4; ++ti)
        acc[ti] = __builtin_amdgcn_mfma_f32_16x16x32_f16(a_x[ti], xf, bC[ti], 0, 0, 0);
#pragma unroll
      for (int ti = 0; ti < 4; ++ti)
        acc[ti] = __builtin_amdgcn_mfma_f32_16x16x32_f16(aU[ti][0], hf0_0, acc[ti], 0, 0, 0);
#pragma unroll
      for (int ti = 0; ti < 4; ++ti)
        acc[ti] = __builtin_amdgcn_mfma_f32_16x16x32_f16(aU[ti][1], hf0_1, acc[ti], 0, 0, 0);

      float hv[4];
#pragma unroll
      for (int r = 0; r < 4; ++r) {
        const float i_ = sigm(acc[0][r]);
        const float f_ = sigm(acc[1][r]);
        const float g_ = tanh_fast(acc[2][r]);
        const float o_ = sigm(acc[3][r]);
        cv[r] = fmaf(f_, cv[r], i_ * g_);
        hv[r] = o_ * tanh_fast(cv[r]);
      }
      const uint2 pv = pk4(hv[0], hv[1], hv[2], hv[3]);
      *(uint2*)&hbuf[p][ar][pub] = pv;   // LDS self-publish (own recurrence)

      // backpressure: slot t&3 holds step t-4; consumer must have loaded it
      // (cf >= t-3) before we overwrite.
      if (t >= PIPE && cached_cons < t - PIPE + 1) {
        int bound = 0;
        do {
          cached_cons = __hip_atomic_load(cf, __ATOMIC_RELAXED, __HIP_MEMORY_SCOPE_AGENT);
          if (cached_cons >= t - PIPE + 1) break;
          __builtin_amdgcn_s_sleep(8);
        } while (++bound < SPIN_MAX);
      }
      const unsigned long long v64 =
          ((unsigned long long)pv.y << 32) | (unsigned long long)pv.x;
      st64(myring + (size_t)(t & (PIPE - 1)) * SLOT_B + ar * 128 + pub, v64);

      __syncthreads();  // per-wave vmcnt drain => all ring stores complete
      if (tid == 0)
        __hip_atomic_store(pf, t + 1, __ATOMIC_RELEASE, __HIP_MEMORY_SCOPE_AGENT);
    }
    return;  // producer writes no output
  }

  // ================= consumer: layer 1 =================
  f16x8 aU[4][2], aV[4][2];
  f32x4 bC[4];
#pragma unroll
  for (int ti = 0; ti < 4; ++ti) {
    const int tile_m = q + 4 * ti;
    const int ga = 16 * tile_m + ar;
#pragma unroll
    for (int kf = 0; kf < 2; ++kf) {
      const int off = ga * HH + kf * 32 + lg * 8;
      aU[ti][kf] = cvt8(w_ih1 + off);
      aV[ti][kf] = cvt8(w_hh1 + off);
    }
#pragma unroll
    for (int r = 0; r < 4; ++r) {
      const int gc = 16 * tile_m + 4 * lg + r;
      bC[ti][r] = b_ih1[gc] + b_hh1[gc];
    }
  }
  float cv[4]  = {0.f, 0.f, 0.f, 0.f};
  float hv1[4] = {0.f, 0.f, 0.f, 0.f};
  int cached_prod = 0;
  __syncthreads();

  // prologue: wait for h0[0], load its fragments
  {
    int bound = 0;
    do {
      cached_prod = __hip_atomic_load(pf, __ATOMIC_ACQUIRE, __HIP_MEMORY_SCOPE_AGENT);
      if (cached_prod >= 1) break;
      __builtin_amdgcn_s_sleep(8);
    } while (++bound < SPIN_MAX);
  }
  union U { unsigned long long u[2]; f16x8 v; };
  U n0, n1;
  {
    const unsigned char* sp = myring + (size_t)0 * SLOT_B + ar * 128;
    n0.u[0] = ld64(sp + rd0); n0.u[1] = ld64(sp + rd0 + 8);
    n1.u[0] = ld64(sp + rd1); n1.u[1] = ld64(sp + rd1 + 8);
  }
  f16x8 hf0_0 = n0.v, hf0_1 = n1.v;

  for (int s = 0; s < TT; ++s) {
    const int p = s & 1, rp = p ^ 1;

    // prefetch h0[s+1] at body top: latency drains at this body's end
    // barrier, ~1000 cyc later -> no stall.
    const bool do_pf = (s + 1 < TT);
    if (do_pf) {
      if (cached_prod < s + 2) {
        int bound = 0;
        do {
          cached_prod = __hip_atomic_load(pf, __ATOMIC_ACQUIRE, __HIP_MEMORY_SCOPE_AGENT);
          if (cached_prod >= s + 2) break;
          __builtin_amdgcn_s_sleep(8);
        } while (++bound < SPIN_MAX);
      }
      __atomic_signal_fence(__ATOMIC_ACQ_REL);
      const unsigned char* sp =
          myring + (size_t)((s + 1) & (PIPE - 1)) * SLOT_B + ar * 128;
      n0.u[0] = ld64(sp + rd0); n0.u[1] = ld64(sp + rd0 + 8);
      n1.u[0] = ld64(sp + rd1); n1.u[1] = ld64(sp + rd1 + 8);
    }

    const f16x8 hf1_0 = *(const f16x8*)&hbuf[rp][ar][rd0];
    const f16x8 hf1_1 = *(const f16x8*)&hbuf[rp][ar][rd1];

    f32x4 acd[4];
#pragma unroll
    for (int ti = 0; ti < 4; ++ti)
      acd[ti] = __builtin_amdgcn_mfma_f32_16x16x32_f16(aU[ti][0], hf0_0, bC[ti], 0, 0, 0);
#pragma unroll
    for (int ti = 0; ti < 4; ++ti)
      acd[ti] = __builtin_amdgcn_mfma_f32_16x16x32_f16(aU[ti][1], hf0_1, acd[ti], 0, 0, 0);
#pragma unroll
    for (int ti = 0; ti < 4; ++ti)
      acd[ti] = __builtin_amdgcn_mfma_f32_16x16x32_f16(aV[ti][0], hf1_0, acd[ti], 0, 0, 0);
#pragma unroll
    for (int ti = 0; ti < 4; ++ti)
      acd[ti] = __builtin_amdgcn_mfma_f32_16x16x32_f16(aV[ti][1], hf1_1, acd[ti], 0, 0, 0);

#pragma unroll
    for (int r = 0; r < 4; ++r) {
      const float i_ = sigm(acd[0][r]);
      const float f_ = sigm(acd[1][r]);
      const float g_ = tanh_fast(acd[2][r]);
      const float o_ = sigm(acd[3][r]);
      cv[r] = fmaf(f_, cv[r], i_ * g_);
      hv1[r] = o_ * tanh_fast(cv[r]);
    }
    *(uint2*)&hbuf[p][ar][pub] = pk4(hv1[0], hv1[1], hv1[2], hv1[3]);

    __syncthreads();  // drains prefetch loads + publishes h1 in LDS
    if (do_pf) { hf0_0 = n0.v; hf0_1 = n1.v; }  // loads completed at barrier
    if (tid == 0)
      __hip_atomic_store(cf, s + 2, __ATOMIC_RELAXED, __HIP_MEMORY_SCOPE_AGENT);
  }

  // head: out[b] = h1[T-1] . w_out + b_out
#pragma unroll
  for (int r = 0; r < 4; ++r) hout[16 * q + 4 * lg + r][ar] = hv1[r];
  __syncthreads();
  if (tid < NB) {
    float v = b_out[0];
    for (int k = 0; k < HH; ++k) v = fmaf(hout[k][tid], w_out[k], v);
    out[tile * NB + tid] = v;
  }
}

extern "C" void kernel_launch(void* const* d_in, const int* in_sizes, int n_in,
                              void* d_out, int out_size, void* d_ws, size_t ws_size,
                              hipStream_t stream) {
  const float* x     = (const float*)d_in[0];
  const float* w_ih0 = (const float*)d_in[1];
  const float* w_hh0 = (const float*)d_in[2];
  const float* b_ih0 = (const float*)d_in[3];
  const float* b_hh0 = (const float*)d_in[4];
  const float* w_ih1 = (const float*)d_in[5];
  const float* w_hh1 = (const float*)d_in[6];
  const float* b_ih1 = (const float*)d_in[7];
  const float* b_hh1 = (const float*)d_in[8];
  const float* w_out = (const float*)d_in[9];
  const float* b_out = (const float*)d_in[10];
  float* out = (float*)d_out;

  int* flags          = (int*)d_ws;
  unsigned char* ring = (unsigned char*)d_ws + RING_OFF;

  // reset handshake flags every launch (graph-capture-safe stream op);
  // stale ring DATA is harmless once flags are zero.
  hipMemsetAsync(d_ws, 0, 2 * NTILE * sizeof(int), stream);

  lstm2_pc<<<dim3(2 * NTILE), dim3(256), 0, stream>>>(
      x, w_ih0, w_hh0, b_ih0, b_hh0,
      w_ih1, w_hh1, b_ih1, b_hh1,
      w_out, b_out, out, flags, ring);
}

// Round 14
// 1420.513 us; speedup vs baseline: 2.9731x; 2.9731x over previous
//
#include <hip/hip_runtime.h>

#define BB 512
#define TT 2048
#define DD 8
#define HH 64
#define NB 4                // batch columns per block (1/4 of the MFMA N-tile)
#define NBLK (BB / NB)      // 128 blocks -> 128 CUs, no cross-CU traffic

typedef _Float16 f16x8 __attribute__((ext_vector_type(8)));
typedef __fp16   fp16x2 __attribute__((ext_vector_type(2)));
typedef float    f32x4 __attribute__((ext_vector_type(4)));

__device__ __forceinline__ float rcpf(float x) { return __builtin_amdgcn_rcpf(x); }
__device__ __forceinline__ float sigm(float x) { return rcpf(1.0f + __expf(-x)); }
__device__ __forceinline__ float tanh_fast(float x) {
  return 1.0f - 2.0f * rcpf(__expf(2.0f * x) + 1.0f);
}
__device__ __forceinline__ f16x8 cvt8(const float* __restrict__ p) {
  f16x8 r;
#pragma unroll
  for (int e = 0; e < 8; ++e) r[e] = (_Float16)p[e];
  return r;
}

// R14: TRANS-PER-LANE PACKING + 4x MORE CUs (no cross-CU traffic).
// Evidence chain: trans pipe is the conserved per-SIMD bottleneck
// (R11: 80 trans-instr x 8cyc = 640 cyc/SIMD-step; doubling waves/SIMD was
// -7%). R13 proved per-step cross-CU handoff costs ~2us (AGENT stores go to
// HBM: WRITE_SIZE=135MB). But trans cost is PER-INSTRUCTION, not per-valid-
// lane: at NB=4 a wave's 16x16 tile holds exactly 64 valid c-updates = 1 per
// lane after an in-wave LDS redistribution -> 10 trans instrs/wave (was 40).
// Batch splits 512/4 = 128 blocks = 128 CUs, embarrassingly parallel.
// Skeleton = R11 (single-barrier, layer-split waves 0-3=L0 / 4-7=L1).
// MFMA B-cols 4-15 read never-written zero LDS rows; their outputs are dead.
// Live-column arithmetic is bitwise identical to R11 (absmax must stay 2^-10).
__global__ void __launch_bounds__(512, 1)
lstm2_mfma(const float* __restrict__ x,
           const float* __restrict__ w_ih0, const float* __restrict__ w_hh0,
           const float* __restrict__ b_ih0, const float* __restrict__ b_hh0,
           const float* __restrict__ w_ih1, const float* __restrict__ w_hh1,
           const float* __restrict__ b_ih1, const float* __restrict__ b_hh1,
           const float* __restrict__ w_out, const float* __restrict__ b_out,
           float* __restrict__ out)
{
  const int tid  = threadIdx.x;
  const int lane = tid & 63;
  const int wq   = tid >> 6;    // wave 0..7
  const int lay  = wq >> 2;     // 0: layer-0 wave, 1: layer-1 wave
  const int q    = wq & 3;      // 16-row k-slice within the layer
  const int lg   = lane >> 4;   // k-group 0..3 (MFMA A/B/C row group)
  const int ar   = lane & 15;   // B-col / C-col (batch); only ar<4 valid
  const int row  = lane >> 2;   // redistributed: hidden row 0..15
  const int col  = lane & 3;    // redistributed: batch col 0..3
  const int tile = blockIdx.x;

  __shared__ __align__(16) unsigned char h0buf[2][16][128];  // fp16, parity dbuf
  __shared__ __align__(16) unsigned char h1buf[2][16][128];  // rows 4..15 stay 0
  __shared__ __align__(16) float stage[8][16][4][4];         // [wave][row][col][gate]
  __shared__ float hout[HH][NB];

  {  // zero both h buffers (h[-1]=0; rows 4..15 must stay 0 forever)
    float* z0 = (float*)h0buf;
    float* z1 = (float*)h1buf;
    for (int i = tid; i < (int)(sizeof(h0buf) / 4); i += 512) { z0[i] = 0.f; z1[i] = 0.f; }
  }

  // ---- static A-fragments (this wave's layer only) + bias C-registers ----
  f16x8 a_x[4];        // L0 only: w_ih0 (k=0..7 live)
  f16x8 aU[4][2];      // L0: w_hh0   |   L1: w_ih1
  f16x8 aV[4][2];      // L1: w_hh1
  f32x4 bC[4];
#pragma unroll
  for (int ti = 0; ti < 4; ++ti) {
    const int tile_m = q + 4 * ti;      // ti: 0=i 1=f 2=g 3=o
    const int ga     = 16 * tile_m + ar;
    f16x8 zf = {};
    a_x[ti] = zf;
    if (lay == 0) {
      if (lg == 0) a_x[ti] = cvt8(w_ih0 + ga * DD);
#pragma unroll
      for (int kf = 0; kf < 2; ++kf) {
        aU[ti][kf] = cvt8(w_hh0 + ga * HH + kf * 32 + lg * 8);
        aV[ti][kf] = zf;
      }
#pragma unroll
      for (int r = 0; r < 4; ++r) {
        const int gc = 16 * tile_m + 4 * lg + r;
        bC[ti][r] = b_ih0[gc] + b_hh0[gc];
      }
    } else {
#pragma unroll
      for (int kf = 0; kf < 2; ++kf) {
        const int off = ga * HH + kf * 32 + lg * 8;
        aU[ti][kf] = cvt8(w_ih1 + off);
        aV[ti][kf] = cvt8(w_hh1 + off);
      }
#pragma unroll
      for (int r = 0; r < 4; ++r) {
        const int gc = 16 * tile_m + 4 * lg + r;
        bC[ti][r] = b_ih1[gc] + b_hh1[gc];
      }
    }
  }

  // x stream (L0 waves; lanes ar>=4 read clamped row 0 of tile, unused)
  const int xr = tile * NB + (ar < NB ? ar : 0);
  const float4* xrow = (const float4*)(x + (size_t)xr * TT * DD);
  float4 xA = make_float4(0, 0, 0, 0), xB = make_float4(0, 0, 0, 0);
  if (lay == 0) { xA = xrow[0]; xB = xrow[1]; }

  float cv  = 0.0f;   // ONE c-update per lane (was 4)
  float hv1 = 0.0f;   // L1: h1[t-1] fp32 for the head

  // publish byte for (k = 16q + row, col):  XOR-swizzled fp16 slot
  const int kk   = 16 * q + row;
  const int pubB = 16 * ((kk >> 3) ^ col) + 2 * (kk & 7);
  // B-frag read offsets (unchanged from R11)
  const int rd0 = 16 * ((0 + lg) ^ (ar & 7));
  const int rd1 = 16 * ((4 + lg) ^ (ar & 7));

  __syncthreads();

  for (int t = 0; t <= TT; ++t) {
    const int p  = t & 1;
    const int rp = p ^ 1;

    if (lay == 0) {
      // ---- L0: h0[t] = act0(bias0 + Wih0@x[t] + Whh0@h0[t-1]) ----
      const f16x8 hf0_0 = *(const f16x8*)&h0buf[rp][ar][rd0];
      const f16x8 hf0_1 = *(const f16x8*)&h0buf[rp][ar][rd1];

      f16x8 xf = {};
      if (lg == 0 && ar < NB) {
        union { fp16x2 h2[4]; f16x8 v; } X;
        X.h2[0] = __builtin_amdgcn_cvt_pkrtz(xA.x, xA.y);
        X.h2[1] = __builtin_amdgcn_cvt_pkrtz(xA.z, xA.w);
        X.h2[2] = __builtin_amdgcn_cvt_pkrtz(xB.x, xB.y);
        X.h2[3] = __builtin_amdgcn_cvt_pkrtz(xB.z, xB.w);
        xf = X.v;
      }
      {
        const int tn = (t + 1 < TT) ? (t + 1) : (TT - 1);
        xA = xrow[2 * tn];
        xB = xrow[2 * tn + 1];
      }

      f32x4 acc[4];
#pragma unroll
      for (int ti = 0; ti < 4; ++ti)
        acc[ti] = __builtin_amdgcn_mfma_f32_16x16x32_f16(a_x[ti], xf, bC[ti], 0, 0, 0);
#pragma unroll
      for (int ti = 0; ti < 4; ++ti)
        acc[ti] = __builtin_amdgcn_mfma_f32_16x16x32_f16(aU[ti][0], hf0_0, acc[ti], 0, 0, 0);
#pragma unroll
      for (int ti = 0; ti < 4; ++ti)
        acc[ti] = __builtin_amdgcn_mfma_f32_16x16x32_f16(aU[ti][1], hf0_1, acc[ti], 0, 0, 0);

      // ---- redistribute gate-quads: 4/lane (16 lanes) -> 1/lane (64) ----
      if (ar < NB) {
#pragma unroll
        for (int r = 0; r < 4; ++r) {
          f32x4 g4;
          g4[0] = acc[0][r]; g4[1] = acc[1][r];
          g4[2] = acc[2][r]; g4[3] = acc[3][r];
          *(f32x4*)&stage[wq][4 * lg + r][ar][0] = g4;   // (row,col) <- (4lg+r, ar)
        }
      }
      asm volatile("s_waitcnt lgkmcnt(0)" ::: "memory");  // in-wave write->read
      const f32x4 ga = *(const f32x4*)&stage[wq][row][col][0];

      // ---- ONE c-update per lane: 10 trans instrs/wave (was 40) ----
      const float i_ = sigm(ga[0]);
      const float f_ = sigm(ga[1]);
      const float g_ = tanh_fast(ga[2]);
      const float o_ = sigm(ga[3]);
      cv = fmaf(f_, cv, i_ * g_);
      const float h = o_ * tanh_fast(cv);
      *(_Float16*)&h0buf[p][col][pubB] = (_Float16)h;
    } else {
      // ---- L1: h1[t-1] = act1(bias1 + Wih1@h0[t-1] + Whh1@h1[t-2]) ----
      const f16x8 hf0_0 = *(const f16x8*)&h0buf[rp][ar][rd0];
      const f16x8 hf0_1 = *(const f16x8*)&h0buf[rp][ar][rd1];
      const f16x8 hf1_0 = *(const f16x8*)&h1buf[rp][ar][rd0];
      const f16x8 hf1_1 = *(const f16x8*)&h1buf[rp][ar][rd1];

      f32x4 acd[4];
#pragma unroll
      for (int ti = 0; ti < 4; ++ti)
        acd[ti] = __builtin_amdgcn_mfma_f32_16x16x32_f16(aU[ti][0], hf0_0, bC[ti], 0, 0, 0);
#pragma unroll
      for (int ti = 0; ti < 4; ++ti)
        acd[ti] = __builtin_amdgcn_mfma_f32_16x16x32_f16(aU[ti][1], hf0_1, acd[ti], 0, 0, 0);
#pragma unroll
      for (int ti = 0; ti < 4; ++ti)
        acd[ti] = __builtin_amdgcn_mfma_f32_16x16x32_f16(aV[ti][0], hf1_0, acd[ti], 0, 0, 0);
#pragma unroll
      for (int ti = 0; ti < 4; ++ti)
        acd[ti] = __builtin_amdgcn_mfma_f32_16x16x32_f16(aV[ti][1], hf1_1, acd[ti], 0, 0, 0);

      if (t != 0) {
        if (ar < NB) {
#pragma unroll
          for (int r = 0; r < 4; ++r) {
            f32x4 g4;
            g4[0] = acd[0][r]; g4[1] = acd[1][r];
            g4[2] = acd[2][r]; g4[3] = acd[3][r];
            *(f32x4*)&stage[wq][4 * lg + r][ar][0] = g4;
          }
        }
        asm volatile("s_waitcnt lgkmcnt(0)" ::: "memory");
        const f32x4 ga = *(const f32x4*)&stage[wq][row][col][0];

        const float i_ = sigm(ga[0]);
        const float f_ = sigm(ga[1]);
        const float g_ = tanh_fast(ga[2]);
        const float o_ = sigm(ga[3]);
        cv = fmaf(f_, cv, i_ * g_);
        hv1 = o_ * tanh_fast(cv);
        *(_Float16*)&h1buf[p][col][pubB] = (_Float16)hv1;
      }
    }

    __syncthreads();  // h0[t], h1[t-1] visible for iter t+1
  }

  // ---- head: out[b] = h1[T-1] . w_out + b_out (L1 lanes hold exact fp32) ----
  if (lay == 1) hout[kk][col] = hv1;
  __syncthreads();
  if (tid < NB) {
    float v = b_out[0];
    for (int k = 0; k < HH; ++k) v = fmaf(hout[k][tid], w_out[k], v);
    out[tile * NB + tid] = v;
  }
}

extern "C" void kernel_launch(void* const* d_in, const int* in_sizes, int n_in,
                              void* d_out, int out_size, void* d_ws, size_t ws_size,
                              hipStream_t stream) {
  const float* x     = (const float*)d_in[0];
  const float* w_ih0 = (const float*)d_in[1];
  const float* w_hh0 = (const float*)d_in[2];
  const float* b_ih0 = (const float*)d_in[3];
  const float* b_hh0 = (const float*)d_in[4];
  const float* w_ih1 = (const float*)d_in[5];
  const float* w_hh1 = (const float*)d_in[6];
  const float* b_ih1 = (const float*)d_in[7];
  const float* b_hh1 = (const float*)d_in[8];
  const float* w_out = (const float*)d_in[9];
  const float* b_out = (const float*)d_in[10];
  float* out = (float*)d_out;

  lstm2_mfma<<<dim3(NBLK), dim3(512), 0, stream>>>(
      x, w_ih0, w_hh0, b_ih0, b_hh0,
      w_ih1, w_hh1, b_ih1, b_hh1,
      w_out, b_out, out);
}

// Round 15
// 1418.033 us; speedup vs baseline: 2.9783x; 1.0017x over previous
//
#include <hip/hip_runtime.h>

#define BB 512
#define TT 2048
#define DD 8
#define HH 64
#define NB 4                // batch columns per block (1/4 of the MFMA N-tile)
#define NBLK (BB / NB)      // 128 blocks -> 128 CUs, no cross-CU traffic

typedef _Float16 f16x8 __attribute__((ext_vector_type(8)));
typedef __fp16   fp16x2 __attribute__((ext_vector_type(2)));
typedef float    f32x4 __attribute__((ext_vector_type(4)));

__device__ __forceinline__ float rcpf(float x) { return __builtin_amdgcn_rcpf(x); }
__device__ __forceinline__ float sigm(float x) { return rcpf(1.0f + __expf(-x)); }
__device__ __forceinline__ float tanh_fast(float x) {
  return 1.0f - 2.0f * rcpf(__expf(2.0f * x) + 1.0f);
}
__device__ __forceinline__ f16x8 cvt8(const float* __restrict__ p) {
  f16x8 r;
#pragma unroll
  for (int e = 0; e < 8; ++e) r[e] = (_Float16)p[e];
  return r;
}

// R15 = R14 + DS-ONLY BARRIER (single-variable change, math untouched).
// R14 measured 1654 cyc/step vs ~650 issue/serial floor. The residue is the
// implicit barrier drain: __syncthreads() emits
//   s_waitcnt vmcnt(0) lgkmcnt(0); s_barrier
// which forces the L0 waves to wait for their NEXT-step global x-prefetch
// (~200-400 cyc L2 latency) at EVERY iteration -- defeating the prefetch.
// Cross-wave correctness only needs the LDS publishes retired:
//   s_waitcnt lgkmcnt(0); s_barrier; sched_barrier(0)
// The x loads now drain at their consumption point next iteration (~1600 cyc
// of slack). LDS is CU-local, so lgkmcnt(0)+s_barrier is sufficient
// visibility; sched_barrier(0) stops the compiler hoisting next-iter LDS
// reads above the barrier (guide rule #18).
__global__ void __launch_bounds__(512, 1)
lstm2_mfma(const float* __restrict__ x,
           const float* __restrict__ w_ih0, const float* __restrict__ w_hh0,
           const float* __restrict__ b_ih0, const float* __restrict__ b_hh0,
           const float* __restrict__ w_ih1, const float* __restrict__ w_hh1,
           const float* __restrict__ b_ih1, const float* __restrict__ b_hh1,
           const float* __restrict__ w_out, const float* __restrict__ b_out,
           float* __restrict__ out)
{
  const int tid  = threadIdx.x;
  const int lane = tid & 63;
  const int wq   = tid >> 6;    // wave 0..7
  const int lay  = wq >> 2;     // 0: layer-0 wave, 1: layer-1 wave
  const int q    = wq & 3;      // 16-row k-slice within the layer
  const int lg   = lane >> 4;   // k-group 0..3 (MFMA A/B/C row group)
  const int ar   = lane & 15;   // B-col / C-col (batch); only ar<4 valid
  const int row  = lane >> 2;   // redistributed: hidden row 0..15
  const int col  = lane & 3;    // redistributed: batch col 0..3
  const int tile = blockIdx.x;

  __shared__ __align__(16) unsigned char h0buf[2][16][128];  // fp16, parity dbuf
  __shared__ __align__(16) unsigned char h1buf[2][16][128];  // rows 4..15 stay 0
  __shared__ __align__(16) float stage[8][16][4][4];         // [wave][row][col][gate]
  __shared__ float hout[HH][NB];

  {  // zero both h buffers (h[-1]=0; rows 4..15 must stay 0 forever)
    float* z0 = (float*)h0buf;
    float* z1 = (float*)h1buf;
    for (int i = tid; i < (int)(sizeof(h0buf) / 4); i += 512) { z0[i] = 0.f; z1[i] = 0.f; }
  }

  // ---- static A-fragments (this wave's layer only) + bias C-registers ----
  f16x8 a_x[4];        // L0 only: w_ih0 (k=0..7 live)
  f16x8 aU[4][2];      // L0: w_hh0   |   L1: w_ih1
  f16x8 aV[4][2];      // L1: w_hh1
  f32x4 bC[4];
#pragma unroll
  for (int ti = 0; ti < 4; ++ti) {
    const int tile_m = q + 4 * ti;      // ti: 0=i 1=f 2=g 3=o
    const int ga     = 16 * tile_m + ar;
    f16x8 zf = {};
    a_x[ti] = zf;
    if (lay == 0) {
      if (lg == 0) a_x[ti] = cvt8(w_ih0 + ga * DD);
#pragma unroll
      for (int kf = 0; kf < 2; ++kf) {
        aU[ti][kf] = cvt8(w_hh0 + ga * HH + kf * 32 + lg * 8);
        aV[ti][kf] = zf;
      }
#pragma unroll
      for (int r = 0; r < 4; ++r) {
        const int gc = 16 * tile_m + 4 * lg + r;
        bC[ti][r] = b_ih0[gc] + b_hh0[gc];
      }
    } else {
#pragma unroll
      for (int kf = 0; kf < 2; ++kf) {
        const int off = ga * HH + kf * 32 + lg * 8;
        aU[ti][kf] = cvt8(w_ih1 + off);
        aV[ti][kf] = cvt8(w_hh1 + off);
      }
#pragma unroll
      for (int r = 0; r < 4; ++r) {
        const int gc = 16 * tile_m + 4 * lg + r;
        bC[ti][r] = b_ih1[gc] + b_hh1[gc];
      }
    }
  }

  // x stream (L0 waves; lanes ar>=4 read clamped row 0 of tile, unused)
  const int xr = tile * NB + (ar < NB ? ar : 0);
  const float4* xrow = (const float4*)(x + (size_t)xr * TT * DD);
  float4 xA = make_float4(0, 0, 0, 0), xB = make_float4(0, 0, 0, 0);
  if (lay == 0) { xA = xrow[0]; xB = xrow[1]; }

  float cv  = 0.0f;   // ONE c-update per lane
  float hv1 = 0.0f;   // L1: h1[t-1] fp32 for the head

  // publish byte for (k = 16q + row, col):  XOR-swizzled fp16 slot
  const int kk   = 16 * q + row;
  const int pubB = 16 * ((kk >> 3) ^ col) + 2 * (kk & 7);
  // B-frag read offsets (unchanged from R11)
  const int rd0 = 16 * ((0 + lg) ^ (ar & 7));
  const int rd1 = 16 * ((4 + lg) ^ (ar & 7));

  __syncthreads();

  for (int t = 0; t <= TT; ++t) {
    const int p  = t & 1;
    const int rp = p ^ 1;

    if (lay == 0) {
      // ---- L0: h0[t] = act0(bias0 + Wih0@x[t] + Whh0@h0[t-1]) ----
      const f16x8 hf0_0 = *(const f16x8*)&h0buf[rp][ar][rd0];
      const f16x8 hf0_1 = *(const f16x8*)&h0buf[rp][ar][rd1];

      f16x8 xf = {};
      if (lg == 0 && ar < NB) {
        union { fp16x2 h2[4]; f16x8 v; } X;
        X.h2[0] = __builtin_amdgcn_cvt_pkrtz(xA.x, xA.y);
        X.h2[1] = __builtin_amdgcn_cvt_pkrtz(xA.z, xA.w);
        X.h2[2] = __builtin_amdgcn_cvt_pkrtz(xB.x, xB.y);
        X.h2[3] = __builtin_amdgcn_cvt_pkrtz(xB.z, xB.w);
        xf = X.v;
      }
      {
        const int tn = (t + 1 < TT) ? (t + 1) : (TT - 1);
        xA = xrow[2 * tn];
        xB = xrow[2 * tn + 1];
      }

      f32x4 acc[4];
#pragma unroll
      for (int ti = 0; ti < 4; ++ti)
        acc[ti] = __builtin_amdgcn_mfma_f32_16x16x32_f16(a_x[ti], xf, bC[ti], 0, 0, 0);
#pragma unroll
      for (int ti = 0; ti < 4; ++ti)
        acc[ti] = __builtin_amdgcn_mfma_f32_16x16x32_f16(aU[ti][0], hf0_0, acc[ti], 0, 0, 0);
#pragma unroll
      for (int ti = 0; ti < 4; ++ti)
        acc[ti] = __builtin_amdgcn_mfma_f32_16x16x32_f16(aU[ti][1], hf0_1, acc[ti], 0, 0, 0);

      // ---- redistribute gate-quads: 4/lane (16 lanes) -> 1/lane (64) ----
      if (ar < NB) {
#pragma unroll
        for (int r = 0; r < 4; ++r) {
          f32x4 g4;
          g4[0] = acc[0][r]; g4[1] = acc[1][r];
          g4[2] = acc[2][r]; g4[3] = acc[3][r];
          *(f32x4*)&stage[wq][4 * lg + r][ar][0] = g4;   // (row,col) <- (4lg+r, ar)
        }
      }
      asm volatile("s_waitcnt lgkmcnt(0)" ::: "memory");  // in-wave write->read
      const f32x4 ga = *(const f32x4*)&stage[wq][row][col][0];

      // ---- ONE c-update per lane: 10 trans instrs/wave ----
      const float i_ = sigm(ga[0]);
      const float f_ = sigm(ga[1]);
      const float g_ = tanh_fast(ga[2]);
      const float o_ = sigm(ga[3]);
      cv = fmaf(f_, cv, i_ * g_);
      const float h = o_ * tanh_fast(cv);
      *(_Float16*)&h0buf[p][col][pubB] = (_Float16)h;
    } else {
      // ---- L1: h1[t-1] = act1(bias1 + Wih1@h0[t-1] + Whh1@h1[t-2]) ----
      const f16x8 hf0_0 = *(const f16x8*)&h0buf[rp][ar][rd0];
      const f16x8 hf0_1 = *(const f16x8*)&h0buf[rp][ar][rd1];
      const f16x8 hf1_0 = *(const f16x8*)&h1buf[rp][ar][rd0];
      const f16x8 hf1_1 = *(const f16x8*)&h1buf[rp][ar][rd1];

      f32x4 acd[4];
#pragma unroll
      for (int ti = 0; ti < 4; ++ti)
        acd[ti] = __builtin_amdgcn_mfma_f32_16x16x32_f16(aU[ti][0], hf0_0, bC[ti], 0, 0, 0);
#pragma unroll
      for (int ti = 0; ti < 4; ++ti)
        acd[ti] = __builtin_amdgcn_mfma_f32_16x16x32_f16(aU[ti][1], hf0_1, acd[ti], 0, 0, 0);
#pragma unroll
      for (int ti = 0; ti < 4; ++ti)
        acd[ti] = __builtin_amdgcn_mfma_f32_16x16x32_f16(aV[ti][0], hf1_0, acd[ti], 0, 0, 0);
#pragma unroll
      for (int ti = 0; ti < 4; ++ti)
        acd[ti] = __builtin_amdgcn_mfma_f32_16x16x32_f16(aV[ti][1], hf1_1, acd[ti], 0, 0, 0);

      if (t != 0) {
        if (ar < NB) {
#pragma unroll
          for (int r = 0; r < 4; ++r) {
            f32x4 g4;
            g4[0] = acd[0][r]; g4[1] = acd[1][r];
            g4[2] = acd[2][r]; g4[3] = acd[3][r];
            *(f32x4*)&stage[wq][4 * lg + r][ar][0] = g4;
          }
        }
        asm volatile("s_waitcnt lgkmcnt(0)" ::: "memory");
        const f32x4 ga = *(const f32x4*)&stage[wq][row][col][0];

        const float i_ = sigm(ga[0]);
        const float f_ = sigm(ga[1]);
        const float g_ = tanh_fast(ga[2]);
        const float o_ = sigm(ga[3]);
        cv = fmaf(f_, cv, i_ * g_);
        hv1 = o_ * tanh_fast(cv);
        *(_Float16*)&h1buf[p][col][pubB] = (_Float16)hv1;
      }
    }

    // ---- DS-only barrier: publishes visible, x-prefetch stays in flight ----
    asm volatile("s_waitcnt lgkmcnt(0)" ::: "memory");
    __builtin_amdgcn_s_barrier();
    __builtin_amdgcn_sched_barrier(0);
  }

  // ---- head: out[b] = h1[T-1] . w_out + b_out (L1 lanes hold exact fp32) ----
  if (lay == 1) hout[kk][col] = hv1;
  __syncthreads();
  if (tid < NB) {
    float v = b_out[0];
    for (int k = 0; k < HH; ++k) v = fmaf(hout[k][tid], w_out[k], v);
    out[tile * NB + tid] = v;
  }
}

extern "C" void kernel_launch(void* const* d_in, const int* in_sizes, int n_in,
                              void* d_out, int out_size, void* d_ws, size_t ws_size,
                              hipStream_t stream) {
  const float* x     = (const float*)d_in[0];
  const float* w_ih0 = (const float*)d_in[1];
  const float* w_hh0 = (const float*)d_in[2];
  const float* b_ih0 = (const float*)d_in[3];
  const float* b_hh0 = (const float*)d_in[4];
  const float* w_ih1 = (const float*)d_in[5];
  const float* w_hh1 = (const float*)d_in[6];
  const float* b_ih1 = (const float*)d_in[7];
  const float* b_hh1 = (const float*)d_in[8];
  const float* w_out = (const float*)d_in[9];
  const float* b_out = (const float*)d_in[10];
  float* out = (float*)d_out;

  lstm2_mfma<<<dim3(NBLK), dim3(512), 0, stream>>>(
      x, w_ih0, w_hh0, b_ih0, b_hh0,
      w_ih1, w_hh1, b_ih1, b_hh1,
      w_out, b_out, out);
}

// Round 16
// 1248.643 us; speedup vs baseline: 3.3824x; 1.1357x over previous
//
#include <hip/hip_runtime.h>

#define BB 512
#define TT 2048
#define DD 8
#define HH 64
#define NB 4                // batch columns per block (1/4 of the MFMA N-tile)
#define NBLK (BB / NB)      // 128 blocks -> 128 CUs, no cross-CU traffic

typedef _Float16 f16x8 __attribute__((ext_vector_type(8)));
typedef __fp16   fp16x2 __attribute__((ext_vector_type(2)));
typedef float    f32x4 __attribute__((ext_vector_type(4)));

__device__ __forceinline__ float rcpf(float x) { return __builtin_amdgcn_rcpf(x); }
__device__ __forceinline__ float sigm(float x) { return rcpf(1.0f + __expf(-x)); }
__device__ __forceinline__ float tanh_fast(float x) {
  return 1.0f - 2.0f * rcpf(__expf(2.0f * x) + 1.0f);
}
__device__ __forceinline__ f16x8 cvt8(const float* __restrict__ p) {
  f16x8 r;
#pragma unroll
  for (int e = 0; e < 8; ++e) r[e] = (_Float16)p[e];
  return r;
}

// R16 = R15 with the gate redistribution moved from an LDS round trip to
// ds_swizzle_b32 (reg->reg through the DS crossbar).
// R15 null killed the barrier-vmcnt theory; refit says the residue is the
// serial chain, whose largest removable link is R14's stage:
//   4x ds_write_b128 -> s_waitcnt lgkmcnt(0) -> ds_read_b128  (~240 cyc,
//   two back-to-back LDS latencies, just to move 4 floats between lanes
//   of the SAME wave).
// The R14 pattern (dest lane l pulls from source 16*(l>>4)+(l&3)) is
// BitMode swizzle offset 0x0013 (and=0x13,or=0,xor=0; same for both
// 32-lane halves). 16 independent swizzles (one DS latency, pipelined)
// + 12 cndmask (loop-invariant masks) replace the round trip. Dest lanes
// pull only from source lanes with ar=(l&3)<4, so dead-column garbage never
// propagates. Per-(row,col) arithmetic identical -> absmax must stay 2^-10.
// Lane->update remap: kk = 16q + 4*(lane>>4) + ((lane>>2)&3), col = lane&3.
__global__ void __launch_bounds__(512, 1)
lstm2_mfma(const float* __restrict__ x,
           const float* __restrict__ w_ih0, const float* __restrict__ w_hh0,
           const float* __restrict__ b_ih0, const float* __restrict__ b_hh0,
           const float* __restrict__ w_ih1, const float* __restrict__ w_hh1,
           const float* __restrict__ b_ih1, const float* __restrict__ b_hh1,
           const float* __restrict__ w_out, const float* __restrict__ b_out,
           float* __restrict__ out)
{
  const int tid  = threadIdx.x;
  const int lane = tid & 63;
  const int wq   = tid >> 6;    // wave 0..7
  const int lay  = wq >> 2;     // 0: layer-0 wave, 1: layer-1 wave
  const int q    = wq & 3;      // 16-row k-slice within the layer
  const int lg   = lane >> 4;   // k-group 0..3 (MFMA A/B/C row group)
  const int ar   = lane & 15;   // B-col / C-col (batch); only ar<4 valid
  const int col  = lane & 3;    // redistributed: batch col 0..3
  const int rsel = (lane >> 2) & 3;  // which source register r' this lane takes
  const int tile = blockIdx.x;

  __shared__ __align__(16) unsigned char h0buf[2][16][128];  // fp16, parity dbuf
  __shared__ __align__(16) unsigned char h1buf[2][16][128];  // rows 4..15 stay 0
  __shared__ float hout[HH][NB];

  {  // zero both h buffers (h[-1]=0; rows 4..15 must stay 0 forever)
    float* z0 = (float*)h0buf;
    float* z1 = (float*)h1buf;
    for (int i = tid; i < (int)(sizeof(h0buf) / 4); i += 512) { z0[i] = 0.f; z1[i] = 0.f; }
  }

  // ---- static A-fragments (this wave's layer only) + bias C-registers ----
  f16x8 a_x[4];        // L0 only: w_ih0 (k=0..7 live)
  f16x8 aU[4][2];      // L0: w_hh0   |   L1: w_ih1
  f16x8 aV[4][2];      // L1: w_hh1
  f32x4 bC[4];
#pragma unroll
  for (int ti = 0; ti < 4; ++ti) {
    const int tile_m = q + 4 * ti;      // ti: 0=i 1=f 2=g 3=o
    const int ga     = 16 * tile_m + ar;
    f16x8 zf = {};
    a_x[ti] = zf;
    if (lay == 0) {
      if (lg == 0) a_x[ti] = cvt8(w_ih0 + ga * DD);
#pragma unroll
      for (int kf = 0; kf < 2; ++kf) {
        aU[ti][kf] = cvt8(w_hh0 + ga * HH + kf * 32 + lg * 8);
        aV[ti][kf] = zf;
      }
#pragma unroll
      for (int r = 0; r < 4; ++r) {
        const int gc = 16 * tile_m + 4 * lg + r;
        bC[ti][r] = b_ih0[gc] + b_hh0[gc];
      }
    } else {
#pragma unroll
      for (int kf = 0; kf < 2; ++kf) {
        const int off = ga * HH + kf * 32 + lg * 8;
        aU[ti][kf] = cvt8(w_ih1 + off);
        aV[ti][kf] = cvt8(w_hh1 + off);
      }
#pragma unroll
      for (int r = 0; r < 4; ++r) {
        const int gc = 16 * tile_m + 4 * lg + r;
        bC[ti][r] = b_ih1[gc] + b_hh1[gc];
      }
    }
  }

  // x stream (L0 waves; lanes ar>=4 read clamped row 0 of tile, unused)
  const int xr = tile * NB + (ar < NB ? ar : 0);
  const float4* xrow = (const float4*)(x + (size_t)xr * TT * DD);
  float4 xA = make_float4(0, 0, 0, 0), xB = make_float4(0, 0, 0, 0);
  if (lay == 0) { xA = xrow[0]; xB = xrow[1]; }

  float cv  = 0.0f;   // ONE c-update per lane
  float hv1 = 0.0f;   // L1: h1[t-1] fp32 for the head

  // this lane's (row, col) after swizzle redistribution:
  //   row kk = 16q + 4*(lane>>4) + rsel, col = lane&3
  const int kk   = 16 * q + 4 * (lane >> 4) + rsel;
  const int pubB = 16 * ((kk >> 3) ^ col) + 2 * (kk & 7);
  // B-frag read offsets (unchanged)
  const int rd0 = 16 * ((0 + lg) ^ (ar & 7));
  const int rd1 = 16 * ((4 + lg) ^ (ar & 7));

  __syncthreads();

  for (int t = 0; t <= TT; ++t) {
    const int p  = t & 1;
    const int rp = p ^ 1;

    if (lay == 0) {
      // ---- L0: h0[t] = act0(bias0 + Wih0@x[t] + Whh0@h0[t-1]) ----
      const f16x8 hf0_0 = *(const f16x8*)&h0buf[rp][ar][rd0];
      const f16x8 hf0_1 = *(const f16x8*)&h0buf[rp][ar][rd1];

      f16x8 xf = {};
      if (lg == 0 && ar < NB) {
        union { fp16x2 h2[4]; f16x8 v; } X;
        X.h2[0] = __builtin_amdgcn_cvt_pkrtz(xA.x, xA.y);
        X.h2[1] = __builtin_amdgcn_cvt_pkrtz(xA.z, xA.w);
        X.h2[2] = __builtin_amdgcn_cvt_pkrtz(xB.x, xB.y);
        X.h2[3] = __builtin_amdgcn_cvt_pkrtz(xB.z, xB.w);
        xf = X.v;
      }
      {
        const int tn = (t + 1 < TT) ? (t + 1) : (TT - 1);
        xA = xrow[2 * tn];
        xB = xrow[2 * tn + 1];
      }

      f32x4 acc[4];
#pragma unroll
      for (int ti = 0; ti < 4; ++ti)
        acc[ti] = __builtin_amdgcn_mfma_f32_16x16x32_f16(a_x[ti], xf, bC[ti], 0, 0, 0);
#pragma unroll
      for (int ti = 0; ti < 4; ++ti)
        acc[ti] = __builtin_amdgcn_mfma_f32_16x16x32_f16(aU[ti][0], hf0_0, acc[ti], 0, 0, 0);
#pragma unroll
      for (int ti = 0; ti < 4; ++ti)
        acc[ti] = __builtin_amdgcn_mfma_f32_16x16x32_f16(aU[ti][1], hf0_1, acc[ti], 0, 0, 0);

      // ---- redistribute 4/lane -> 1/lane via ds_swizzle (no LDS array) ----
      f32x4 ga;
#pragma unroll
      for (int ti = 0; ti < 4; ++ti) {
        const int s0 = __builtin_amdgcn_ds_swizzle(__float_as_int(acc[ti][0]), 0x0013);
        const int s1 = __builtin_amdgcn_ds_swizzle(__float_as_int(acc[ti][1]), 0x0013);
        const int s2 = __builtin_amdgcn_ds_swizzle(__float_as_int(acc[ti][2]), 0x0013);
        const int s3 = __builtin_amdgcn_ds_swizzle(__float_as_int(acc[ti][3]), 0x0013);
        const int v01 = (rsel & 1) ? s1 : s0;
        const int v23 = (rsel & 1) ? s3 : s2;
        ga[ti] = __int_as_float((rsel & 2) ? v23 : v01);
      }

      // ---- ONE c-update per lane: 10 trans instrs/wave ----
      const float i_ = sigm(ga[0]);
      const float f_ = sigm(ga[1]);
      const float g_ = tanh_fast(ga[2]);
      const float o_ = sigm(ga[3]);
      cv = fmaf(f_, cv, i_ * g_);
      const float h = o_ * tanh_fast(cv);
      *(_Float16*)&h0buf[p][col][pubB] = (_Float16)h;
    } else {
      // ---- L1: h1[t-1] = act1(bias1 + Wih1@h0[t-1] + Whh1@h1[t-2]) ----
      const f16x8 hf0_0 = *(const f16x8*)&h0buf[rp][ar][rd0];
      const f16x8 hf0_1 = *(const f16x8*)&h0buf[rp][ar][rd1];
      const f16x8 hf1_0 = *(const f16x8*)&h1buf[rp][ar][rd0];
      const f16x8 hf1_1 = *(const f16x8*)&h1buf[rp][ar][rd1];

      f32x4 acd[4];
#pragma unroll
      for (int ti = 0; ti < 4; ++ti)
        acd[ti] = __builtin_amdgcn_mfma_f32_16x16x32_f16(aU[ti][0], hf0_0, bC[ti], 0, 0, 0);
#pragma unroll
      for (int ti = 0; ti < 4; ++ti)
        acd[ti] = __builtin_amdgcn_mfma_f32_16x16x32_f16(aU[ti][1], hf0_1, acd[ti], 0, 0, 0);
#pragma unroll
      for (int ti = 0; ti < 4; ++ti)
        acd[ti] = __builtin_amdgcn_mfma_f32_16x16x32_f16(aV[ti][0], hf1_0, acd[ti], 0, 0, 0);
#pragma unroll
      for (int ti = 0; ti < 4; ++ti)
        acd[ti] = __builtin_amdgcn_mfma_f32_16x16x32_f16(aV[ti][1], hf1_1, acd[ti], 0, 0, 0);

      if (t != 0) {
        f32x4 ga;
#pragma unroll
        for (int ti = 0; ti < 4; ++ti) {
          const int s0 = __builtin_amdgcn_ds_swizzle(__float_as_int(acd[ti][0]), 0x0013);
          const int s1 = __builtin_amdgcn_ds_swizzle(__float_as_int(acd[ti][1]), 0x0013);
          const int s2 = __builtin_amdgcn_ds_swizzle(__float_as_int(acd[ti][2]), 0x0013);
          const int s3 = __builtin_amdgcn_ds_swizzle(__float_as_int(acd[ti][3]), 0x0013);
          const int v01 = (rsel & 1) ? s1 : s0;
          const int v23 = (rsel & 1) ? s3 : s2;
          ga[ti] = __int_as_float((rsel & 2) ? v23 : v01);
        }

        const float i_ = sigm(ga[0]);
        const float f_ = sigm(ga[1]);
        const float g_ = tanh_fast(ga[2]);
        const float o_ = sigm(ga[3]);
        cv = fmaf(f_, cv, i_ * g_);
        hv1 = o_ * tanh_fast(cv);
        *(_Float16*)&h1buf[p][col][pubB] = (_Float16)hv1;
      }
    }

    // ---- DS-only barrier: publishes visible, x-prefetch stays in flight ----
    asm volatile("s_waitcnt lgkmcnt(0)" ::: "memory");
    __builtin_amdgcn_s_barrier();
    __builtin_amdgcn_sched_barrier(0);
  }

  // ---- head: out[b] = h1[T-1] . w_out + b_out (L1 lanes hold exact fp32) ----
  if (lay == 1) hout[kk][col] = hv1;
  __syncthreads();
  if (tid < NB) {
    float v = b_out[0];
    for (int k = 0; k < HH; ++k) v = fmaf(hout[k][tid], w_out[k], v);
    out[tile * NB + tid] = v;
  }
}

extern "C" void kernel_launch(void* const* d_in, const int* in_sizes, int n_in,
                              void* d_out, int out_size, void* d_ws, size_t ws_size,
                              hipStream_t stream) {
  const float* x     = (const float*)d_in[0];
  const float* w_ih0 = (const float*)d_in[1];
  const float* w_hh0 = (const float*)d_in[2];
  const float* b_ih0 = (const float*)d_in[3];
  const float* b_hh0 = (const float*)d_in[4];
  const float* w_ih1 = (const float*)d_in[5];
  const float* w_hh1 = (const float*)d_in[6];
  const float* b_ih1 = (const float*)d_in[7];
  const float* b_hh1 = (const float*)d_in[8];
  const float* w_out = (const float*)d_in[9];
  const float* b_out = (const float*)d_in[10];
  float* out = (float*)d_out;

  lstm2_mfma<<<dim3(NBLK), dim3(512), 0, stream>>>(
      x, w_ih0, w_hh0, b_ih0, b_hh0,
      w_ih1, w_hh1, b_ih1, b_hh1,
      w_out, b_out, out);
}